// Round 5
// baseline (852.793 us; speedup 1.0000x reference)
//
#include <hip/hip_runtime.h>

// Orient_Conv: 3x3 orientation-gated conv, 4 orientations + per-pixel argmax.
// B=4, CIN=COUT=32, H=W=128, pad=1.
//
// Gate identity (C=cos(wr), S=sin(wr), r0=cos(th), r1=sin(th)):
//   u = C*r0+S*r1, v = C*r1-S*r0
//   gates: o0=relu(u), o1=relu(v), o2=relu(-u)=relu(u)-u, o3=relu(v)-v
// Rotated weights at tap (i,j): w0=w[i][j], w1=w[2-j][i], w2=w[2-i][2-j],
//   w3=w[j][2-i].
//
// R4: PURE SCALAR fp32 (CDNA4 v_pk_f32 adds no datapath width; spec 157.3 TF
// = scalar rate — packing only added splat movs). 16 scalar VALU/element is
// the floor (123 us). Weights per-lane from global table (VGPR operands, no
// splats/SGPR stalls). Staging batched: 8 channels per barrier-pair (8
// barriers total vs 64), loads issued before the barrier for overlap.
// Block = 512 thr = 32 oc x 16 pxg over (b,h,64px); thread = 4 px x 1 oc.
// __launch_bounds__(512,8) pins VGPR<=64 -> 8 waves/SIMD.

#define B_    4
#define CIN_  32
#define COUT_ 32
#define H_    128
#define W_    128
#define HW_   (H_ * W_)
#define OUTSZ_ (B_ * COUT_ * H_ * W_)

// tab layout: [cc][tap][oc][8] = {C,S,w0,w1,w2,w3,0,0}
__global__ __launch_bounds__(256)
void build_wtab(const float* __restrict__ w, const float* __restrict__ wr,
                float* __restrict__ tab)
{
    int idx = blockIdx.x * 256 + threadIdx.x;   // ((cc*9+tap)<<5)|oc
    if (idx >= CIN_ * 9 * COUT_) return;        // 9216
    int oc  = idx & 31;
    int t2  = idx >> 5;
    int tap = t2 % 9;
    int cc  = t2 / 9;
    int i = tap / 3, j = tap - i * 3;
    int base = (oc * CIN_ + cc) * 9;
    float w0 = w[base + i * 3 + j];
    float w1 = w[base + (2 - j) * 3 + i];
    float w2 = w[base + (2 - i) * 3 + (2 - j)];
    float w3 = w[base + j * 3 + (2 - i)];
    float S, C;
    sincosf(wr[base + i * 3 + j], &S, &C);
    float* dst = tab + (size_t)idx * 8;
    dst[0] = C;  dst[1] = S;
    dst[2] = w0; dst[3] = w1;
    dst[4] = w2; dst[5] = w3;
    dst[6] = 0.0f; dst[7] = 0.0f;
}

#define NC_   8                       // channels staged per barrier-pair
#define SLOTS (NC_ * 3 * 68)          // 1632 floats per array per group

__global__ __launch_bounds__(512, 8)
void orient_conv_kernel(const float* __restrict__ f,
                        const float* __restrict__ r0,
                        const float* __restrict__ r1,
                        const float* __restrict__ tab,
                        float* __restrict__ out)
{
    // layout per array: [cc_local(8)][row(3)][col(68)], flat index = slot
    __shared__ float sF[SLOTS], sR0[SLOTS], sR1[SLOTS];

    const int tid   = threadIdx.x;
    const int oc    = tid & 31;
    const int pxg   = tid >> 5;            // 0..15
    const int px0   = pxg << 2;            // 4 px per thread
    const int bid   = blockIdx.x;          // 0..1023
    const int b     = bid >> 8;
    const int rem   = bid & 255;
    const int h     = rem >> 1;
    const int wbase = (rem & 1) << 6;      // 0 or 64

    // ---- staging descriptors: up to 4 slots/thread (slot = tid + 512k) ----
    int      goff[4];
    unsigned msk[4];
#pragma unroll
    for (int k = 0; k < 4; ++k) {
        int s = tid + (k << 9);
        if (s < SLOTS) {
            int cc_l = s / 204;
            int r2   = s - cc_l * 204;
            int row  = r2 / 68;
            int col  = r2 - row * 68;
            int gh = h + row - 1;
            int gw = wbase + col - 1;
            bool ok = ((unsigned)gh < (unsigned)H_) & ((unsigned)gw < (unsigned)W_);
            goff[k] = ok ? (cc_l * HW_ + gh * W_ + gw) : 0;
            msk[k]  = ok ? 0xFFFFFFFFu : 0u;
        } else { goff[k] = 0; msk[k] = 0u; }
    }
    const bool have3 = (tid + 1536) < SLOTS;   // tid < 96
    const int chanBase = b * (CIN_ * HW_);

    float acc[4][4];                       // [px][orient]
#pragma unroll
    for (int p = 0; p < 4; ++p)
#pragma unroll
        for (int o = 0; o < 4; ++o) acc[p][o] = 0.0f;

#pragma unroll 1
    for (int g = 0; g < CIN_ / NC_; ++g) {
        // ---- issue global loads (no LDS dep -> overlap prev compute) ----
        const int gb = chanBase + g * (NC_ * HW_);
        float tF[4], tA[4], tB[4];
#pragma unroll
        for (int k = 0; k < 3; ++k) {
            tF[k] = f [gb + goff[k]];
            tA[k] = r0[gb + goff[k]];
            tB[k] = r1[gb + goff[k]];
        }
        if (have3) {
            tF[3] = f [gb + goff[3]];
            tA[3] = r0[gb + goff[3]];
            tB[3] = r1[gb + goff[3]];
        }
        __syncthreads();   // previous group's compute done
#pragma unroll
        for (int k = 0; k < 3; ++k) {
            int s = tid + (k << 9);
            sF [s] = __uint_as_float(__float_as_uint(tF[k]) & msk[k]);
            sR0[s] = __uint_as_float(__float_as_uint(tA[k]) & msk[k]);
            sR1[s] = __uint_as_float(__float_as_uint(tB[k]) & msk[k]);
        }
        if (have3) {
            int s = tid + 1536;
            sF [s] = __uint_as_float(__float_as_uint(tF[3]) & msk[3]);
            sR0[s] = __uint_as_float(__float_as_uint(tA[3]) & msk[3]);
            sR1[s] = __uint_as_float(__float_as_uint(tB[3]) & msk[3]);
        }
        __syncthreads();

        // ---- compute the NC_ staged channels ----
#pragma unroll 1
        for (int cl = 0; cl < NC_; ++cl) {
            const int cc = g * NC_ + cl;
            const float* wcc = tab + ((size_t)(cc * 9) * 32 + oc) * 8;
#pragma unroll
            for (int i = 0; i < 3; ++i) {
                const int bi = cl * 204 + i * 68 + px0;
                float4 F4 = *reinterpret_cast<const float4*>(&sF [bi]);
                float2 F2 = *reinterpret_cast<const float2*>(&sF [bi + 4]);
                float4 A4 = *reinterpret_cast<const float4*>(&sR0[bi]);
                float2 A2 = *reinterpret_cast<const float2*>(&sR0[bi + 4]);
                float4 B4 = *reinterpret_cast<const float4*>(&sR1[bi]);
                float2 B2 = *reinterpret_cast<const float2*>(&sR1[bi + 4]);
                const float fin[6]  = {F4.x, F4.y, F4.z, F4.w, F2.x, F2.y};
                const float ain[6]  = {A4.x, A4.y, A4.z, A4.w, A2.x, A2.y};
                const float bin_[6] = {B4.x, B4.y, B4.z, B4.w, B2.x, B2.y};
#pragma unroll
                for (int j = 0; j < 3; ++j) {
                    const float* wp = wcc + (i * 3 + j) * 256;
                    float4 W4 = *reinterpret_cast<const float4*>(wp);
                    float2 W2 = *reinterpret_cast<const float2*>(wp + 4);
                    const float C  = W4.x, S  = W4.y;
                    const float w0 = W4.z, w1 = W4.w;
                    const float w2 = W2.x, w3 = W2.y;
#pragma unroll
                    for (int p = 0; p < 4; ++p) {
                        const float fv  = fin [p + j];
                        const float r0v = ain [p + j];
                        const float r1v = bin_[p + j];
                        float u  = fmaf(C, r0v, S * r1v);
                        float vv = fmaf(C, r1v, -(S * r0v));
                        float g0 = fmaxf(u,  0.0f);
                        float g1 = fmaxf(vv, 0.0f);
                        float g2 = g0 - u;     // relu(-u), exact
                        float g3 = g1 - vv;    // relu(-v), exact
                        acc[p][0] = fmaf(fv * g0, w0, acc[p][0]);
                        acc[p][1] = fmaf(fv * g1, w1, acc[p][1]);
                        acc[p][2] = fmaf(fv * g2, w2, acc[p][2]);
                        acc[p][3] = fmaf(fv * g3, w3, acc[p][3]);
                    }
                }
            }
        }
    }

    // ---- epilogue: max/argmax over orientations (first-max tie-break) ----
    const float cosv[4] = {1.0f, -4.37113883e-08f, -1.0f, 1.19248806e-08f};
    const float sinv[4] = {0.0f, 1.0f, -8.74227766e-08f, -1.0f};
#pragma unroll
    for (int p = 0; p < 4; ++p) {
        int wcol = wbase + px0 + p;
        float a0 = acc[p][0], a1 = acc[p][1];
        float a2 = acc[p][2], a3 = acc[p][3];
        float best = a0; int bi = 0;
        if (a1 > best) { best = a1; bi = 1; }
        if (a2 > best) { best = a2; bi = 2; }
        if (a3 > best) { best = a3; bi = 3; }
        size_t o = ((size_t)(b * COUT_ + oc) * H_ + h) * W_ + wcol;
        out[o]              = best;
        out[o + OUTSZ_]     = cosv[bi];
        out[o + 2 * OUTSZ_] = sinv[bi];
    }
}

extern "C" void kernel_launch(void* const* d_in, const int* in_sizes, int n_in,
                              void* d_out, int out_size, void* d_ws, size_t ws_size,
                              hipStream_t stream)
{
    const float* f  = (const float*)d_in[0];
    const float* r0 = (const float*)d_in[1];
    const float* r1 = (const float*)d_in[2];
    const float* w  = (const float*)d_in[3];
    const float* wr = (const float*)d_in[4];
    float* out = (float*)d_out;
    float* tab = (float*)d_ws;    // 294912 B

    build_wtab<<<dim3(36), dim3(256), 0, stream>>>(w, wr, tab);
    orient_conv_kernel<<<dim3(B_ * H_ * 2), dim3(512), 0, stream>>>(
        f, r0, r1, tab, out);
}

// Round 6
// 302.626 us; speedup vs baseline: 2.8180x; 2.8180x over previous
//
#include <hip/hip_runtime.h>

// Orient_Conv: 3x3 orientation-gated conv, 4 orientations + per-pixel argmax.
// B=4, CIN=COUT=32, H=W=128, pad=1.
//
// Gate identity (C=cos(wr), S=sin(wr), r0=cos(th), r1=sin(th)):
//   u = C*r0+S*r1, v = C*r1-S*r0
//   gates: o0=relu(u), o1=relu(v), o2=relu(-u)=relu(u)-u, o3=relu(v)-v
// Rotated weights at tap (i,j): w0=w[i][j], w1=w[2-j][i], w2=w[2-i][2-j],
//   w3=w[j][2-i].
//
// R5 = R4 structure, spill fixed: __launch_bounds__(512,4) (VGPR cap 128;
// R4's (512,8) cap of 64 caused a 2.1 GB scratch catastrophe). Scalar fp32
// core (16 VALU ops/element = 123 us floor; CDNA4 v_pk_f32 adds no width).
// Weights per-lane from precomputed global table (L1-hot, VMEM pipe).
// Staging: 8 channels per barrier-pair; group g+1's loads are issued BEFORE
// group g's compute so the barrier's vmcnt drain is free.
// Block = 512 thr = 32 oc x 16 pxg over (b,h,64px); thread = 4 px x 1 oc.

#define B_    4
#define CIN_  32
#define COUT_ 32
#define H_    128
#define W_    128
#define HW_   (H_ * W_)
#define OUTSZ_ (B_ * COUT_ * H_ * W_)

// tab layout: [cc][tap][oc][8] = {C,S,w0,w1,w2,w3,0,0}
__global__ __launch_bounds__(256)
void build_wtab(const float* __restrict__ w, const float* __restrict__ wr,
                float* __restrict__ tab)
{
    int idx = blockIdx.x * 256 + threadIdx.x;   // ((cc*9+tap)<<5)|oc
    if (idx >= CIN_ * 9 * COUT_) return;        // 9216
    int oc  = idx & 31;
    int t2  = idx >> 5;
    int tap = t2 % 9;
    int cc  = t2 / 9;
    int i = tap / 3, j = tap - i * 3;
    int base = (oc * CIN_ + cc) * 9;
    float w0 = w[base + i * 3 + j];
    float w1 = w[base + (2 - j) * 3 + i];
    float w2 = w[base + (2 - i) * 3 + (2 - j)];
    float w3 = w[base + j * 3 + (2 - i)];
    float S, C;
    sincosf(wr[base + i * 3 + j], &S, &C);
    float* dst = tab + (size_t)idx * 8;
    dst[0] = C;  dst[1] = S;
    dst[2] = w0; dst[3] = w1;
    dst[4] = w2; dst[5] = w3;
    dst[6] = 0.0f; dst[7] = 0.0f;
}

#define NC_   8                       // channels staged per barrier-pair
#define NG_   (CIN_ / NC_)            // 4 groups
#define SLOTS (NC_ * 3 * 68)          // 1632 floats per array per group

__global__ __launch_bounds__(512, 4)
void orient_conv_kernel(const float* __restrict__ f,
                        const float* __restrict__ r0,
                        const float* __restrict__ r1,
                        const float* __restrict__ tab,
                        float* __restrict__ out)
{
    // layout per array: [cc_local(8)][row(3)][col(68)], flat index = slot
    __shared__ float sF[SLOTS], sR0[SLOTS], sR1[SLOTS];

    const int tid   = threadIdx.x;
    const int oc    = tid & 31;
    const int pxg   = tid >> 5;            // 0..15
    const int px0   = pxg << 2;            // 4 px per thread
    const int bid   = blockIdx.x;          // 0..1023
    const int b     = bid >> 8;
    const int rem   = bid & 255;
    const int h     = rem >> 1;
    const int wbase = (rem & 1) << 6;      // 0 or 64

    // ---- staging descriptors: up to 4 slots/thread (slot = tid + 512k) ----
    int      goff[4];
    unsigned msk[4];
#pragma unroll
    for (int k = 0; k < 4; ++k) {
        int s = tid + (k << 9);
        if (s < SLOTS) {
            int cc_l = s / 204;
            int r2   = s - cc_l * 204;
            int row  = r2 / 68;
            int col  = r2 - row * 68;
            int gh = h + row - 1;
            int gw = wbase + col - 1;
            bool ok = ((unsigned)gh < (unsigned)H_) & ((unsigned)gw < (unsigned)W_);
            goff[k] = ok ? (cc_l * HW_ + gh * W_ + gw) : 0;
            msk[k]  = ok ? 0xFFFFFFFFu : 0u;
        } else { goff[k] = 0; msk[k] = 0u; }
    }
    const bool have3 = (tid + 1536) < SLOTS;   // tid < 96
    const int chanBase = b * (CIN_ * HW_);

    float acc[4][4];                       // [px][orient]
#pragma unroll
    for (int p = 0; p < 4; ++p)
#pragma unroll
        for (int o = 0; o < 4; ++o) acc[p][o] = 0.0f;

    // ---- prefetch group 0 ----
    float tF[4], tA[4], tB[4];
    {
        const int gb = chanBase;
#pragma unroll
        for (int k = 0; k < 3; ++k) {
            tF[k] = f [gb + goff[k]];
            tA[k] = r0[gb + goff[k]];
            tB[k] = r1[gb + goff[k]];
        }
        if (have3) {
            tF[3] = f [gb + goff[3]];
            tA[3] = r0[gb + goff[3]];
            tB[3] = r1[gb + goff[3]];
        }
    }

#pragma unroll 1
    for (int g = 0; g < NG_; ++g) {
        __syncthreads();   // all waves done reading LDS of group g-1
#pragma unroll
        for (int k = 0; k < 3; ++k) {
            int s = tid + (k << 9);
            sF [s] = __uint_as_float(__float_as_uint(tF[k]) & msk[k]);
            sR0[s] = __uint_as_float(__float_as_uint(tA[k]) & msk[k]);
            sR1[s] = __uint_as_float(__float_as_uint(tB[k]) & msk[k]);
        }
        if (have3) {
            int s = tid + 1536;
            sF [s] = __uint_as_float(__float_as_uint(tF[3]) & msk[3]);
            sR0[s] = __uint_as_float(__float_as_uint(tA[3]) & msk[3]);
            sR1[s] = __uint_as_float(__float_as_uint(tB[3]) & msk[3]);
        }
        __syncthreads();

        // ---- prefetch group g+1 (in flight during compute below) ----
        if (g + 1 < NG_) {
            const int gb = chanBase + (g + 1) * (NC_ * HW_);
#pragma unroll
            for (int k = 0; k < 3; ++k) {
                tF[k] = f [gb + goff[k]];
                tA[k] = r0[gb + goff[k]];
                tB[k] = r1[gb + goff[k]];
            }
            if (have3) {
                tF[3] = f [gb + goff[3]];
                tA[3] = r0[gb + goff[3]];
                tB[3] = r1[gb + goff[3]];
            }
        }

        // ---- compute the NC_ staged channels ----
#pragma unroll 1
        for (int cl = 0; cl < NC_; ++cl) {
            const int cc = g * NC_ + cl;
            const float* wcc = tab + ((size_t)(cc * 9) * 32 + oc) * 8;
#pragma unroll
            for (int i = 0; i < 3; ++i) {
                const int bi = cl * 204 + i * 68 + px0;
                float4 F4 = *reinterpret_cast<const float4*>(&sF [bi]);
                float2 F2 = *reinterpret_cast<const float2*>(&sF [bi + 4]);
                float4 A4 = *reinterpret_cast<const float4*>(&sR0[bi]);
                float2 A2 = *reinterpret_cast<const float2*>(&sR0[bi + 4]);
                float4 B4 = *reinterpret_cast<const float4*>(&sR1[bi]);
                float2 B2 = *reinterpret_cast<const float2*>(&sR1[bi + 4]);
                const float fin[6]  = {F4.x, F4.y, F4.z, F4.w, F2.x, F2.y};
                const float ain[6]  = {A4.x, A4.y, A4.z, A4.w, A2.x, A2.y};
                const float bin_[6] = {B4.x, B4.y, B4.z, B4.w, B2.x, B2.y};
#pragma unroll
                for (int j = 0; j < 3; ++j) {
                    const float* wp = wcc + (i * 3 + j) * 256;
                    float4 W4 = *reinterpret_cast<const float4*>(wp);
                    float2 W2 = *reinterpret_cast<const float2*>(wp + 4);
                    const float C  = W4.x, S  = W4.y;
                    const float w0 = W4.z, w1 = W4.w;
                    const float w2 = W2.x, w3 = W2.y;
#pragma unroll
                    for (int p = 0; p < 4; ++p) {
                        const float fv  = fin [p + j];
                        const float r0v = ain [p + j];
                        const float r1v = bin_[p + j];
                        float u  = fmaf(C, r0v, S * r1v);
                        float vv = fmaf(C, r1v, -(S * r0v));
                        float g0 = fmaxf(u,  0.0f);
                        float g1 = fmaxf(vv, 0.0f);
                        float g2 = g0 - u;     // relu(-u), exact
                        float g3 = g1 - vv;    // relu(-v), exact
                        acc[p][0] = fmaf(fv * g0, w0, acc[p][0]);
                        acc[p][1] = fmaf(fv * g1, w1, acc[p][1]);
                        acc[p][2] = fmaf(fv * g2, w2, acc[p][2]);
                        acc[p][3] = fmaf(fv * g3, w3, acc[p][3]);
                    }
                }
            }
        }
    }

    // ---- epilogue: max/argmax over orientations (first-max tie-break) ----
    const float cosv[4] = {1.0f, -4.37113883e-08f, -1.0f, 1.19248806e-08f};
    const float sinv[4] = {0.0f, 1.0f, -8.74227766e-08f, -1.0f};
#pragma unroll
    for (int p = 0; p < 4; ++p) {
        int wcol = wbase + px0 + p;
        float a0 = acc[p][0], a1 = acc[p][1];
        float a2 = acc[p][2], a3 = acc[p][3];
        float best = a0; int bi = 0;
        if (a1 > best) { best = a1; bi = 1; }
        if (a2 > best) { best = a2; bi = 2; }
        if (a3 > best) { best = a3; bi = 3; }
        size_t o = ((size_t)(b * COUT_ + oc) * H_ + h) * W_ + wcol;
        out[o]              = best;
        out[o + OUTSZ_]     = cosv[bi];
        out[o + 2 * OUTSZ_] = sinv[bi];
    }
}

extern "C" void kernel_launch(void* const* d_in, const int* in_sizes, int n_in,
                              void* d_out, int out_size, void* d_ws, size_t ws_size,
                              hipStream_t stream)
{
    const float* f  = (const float*)d_in[0];
    const float* r0 = (const float*)d_in[1];
    const float* r1 = (const float*)d_in[2];
    const float* w  = (const float*)d_in[3];
    const float* wr = (const float*)d_in[4];
    float* out = (float*)d_out;
    float* tab = (float*)d_ws;    // 294912 B

    build_wtab<<<dim3(36), dim3(256), 0, stream>>>(w, wr, tab);
    orient_conv_kernel<<<dim3(B_ * H_ * 2), dim3(512), 0, stream>>>(
        f, r0, r1, tab, out);
}